// Round 5
// baseline (2295.390 us; speedup 1.0000x reference)
//
#include <hip/hip_runtime.h>

#define Vn 128
#define En 32
#define Hn 128
#define Bn 4
#define Sn 512
#define G4H 512   // 4*Hn

typedef _Float16 half2v __attribute__((ext_vector_type(2)));

__device__ __forceinline__ float fsigmoid(float x) {
    return 1.0f / (1.0f + __expf(-x));
}

__device__ __forceinline__ float ftanh(float x) {
    float ax = fabsf(x);
    float e  = __expf(2.0f * ax);
    float t  = 1.0f - 2.0f / (e + 1.0f);
    return copysignf(t, x);
}

// packed fp16 dot-2 with fp32 accumulate (v_dot2_f32_f16)
__device__ __forceinline__ float dot2f(float wb, float hb, float acc) {
#if __has_builtin(__builtin_amdgcn_fdot2)
    return __builtin_amdgcn_fdot2(__builtin_bit_cast(half2v, wb),
                                  __builtin_bit_cast(half2v, hb), acc, false);
#else
    half2v a = __builtin_bit_cast(half2v, wb);
    half2v b = __builtin_bit_cast(half2v, hb);
    return acc + (float)a.x * (float)b.x + (float)a.y * (float)b.y;
#endif
}

// ---------------------------------------------------------------------------
// Kernel W: convert W_hh (4H x H fp32, 256 KB) -> fp16 (128 KB), same layout.
// ---------------------------------------------------------------------------
__global__ __launch_bounds__(256) void k_wcvt(
        const float* __restrict__ W, _Float16* __restrict__ Wh) {
    int i = blockIdx.x * 256 + threadIdx.x;   // over 16384 float4s
    float4 w = ((const float4*)W)[i];
    half2v lo = { (_Float16)w.x, (_Float16)w.y };
    half2v hi = { (_Float16)w.z, (_Float16)w.w };
    ((half2v*)Wh)[2 * i]     = lo;
    ((half2v*)Wh)[2 * i + 1] = hi;
}

// ---------------------------------------------------------------------------
// Kernel A': Gtab[v][g] = (b_ih+b_hh)[g] + sum_e emb[v][e] * W_ih[g][e]
// ---------------------------------------------------------------------------
__global__ __launch_bounds__(512) void k_gtab(
        const float* __restrict__ emb, const float* __restrict__ Wih,
        const float* __restrict__ bih, const float* __restrict__ bhh,
        float* __restrict__ Gtab) {
    int v = blockIdx.x;
    int g = threadIdx.x;
    __shared__ float e[En];
    if (g < En) e[g] = emb[v * En + g];
    __syncthreads();
    const float4* wr = (const float4*)(Wih + g * En);
    float acc = bih[g] + bhh[g];
#pragma unroll
    for (int i = 0; i < En / 4; i++) {
        float4 w4 = wr[i];
        acc += w4.x * e[4*i] + w4.y * e[4*i+1] + w4.z * e[4*i+2] + w4.w * e[4*i+3];
    }
    Gtab[v * G4H + g] = acc;
}

// ---------------------------------------------------------------------------
// Kernel B (R9 = R8 + waves_per_eu(2,2)): LSTM recurrence. 512 threads, one
// block per batch, thread (j = tid&127, q = tid>>7) owns 4 gate rows x
// K-quarter q. fp16 weight stream (128 KB/step), v_dot2_f32_f16 compute.
//
// R8 post-mortem: WITHOUT the waves_per_eu pin, the occupancy heuristic
// capped VGPRs at 40 -> the 20 b128 loads/step could not be batched ->
// serial load-use chains, 9640 cyc/step of pure L2 latency (per-CU VALUBusy
// 8%). The launch shape fixes real occupancy at 2 waves/SIMD regardless, so
// (2,2) costs nothing and gives the allocator a 256-VGPR budget to batch all
// 20 loads. AGPR parking (R5/R6) does not apply: weight live ranges are
// intra-iteration (re-loaded each step from asm-laundered pointers), not
// loop-carried.
// Floor: 128 KB/step / 128 B/cy = 1024 cyc/step.
// ---------------------------------------------------------------------------
__global__ __attribute__((amdgpu_flat_work_group_size(512, 512),
                          amdgpu_waves_per_eu(2, 2)))
void k_lstm(
        const _Float16* __restrict__ Wh, const float* __restrict__ Gtab,
        const int* __restrict__ x,
        float* __restrict__ out, float* __restrict__ hT, float* __restrict__ cT) {
    int b   = blockIdx.x;
    int tid = threadIdx.x;
    int j   = tid & 127;
    int q   = tid >> 7;

    __shared__ alignas(16) _Float16 hbuf[Hn];   // fp16 mirror of h
    __shared__ float part[16][Hn];
    __shared__ int   xb[Sn];

    xb[tid] = x[b * Sn + tid];
    if (tid < Hn) hbuf[tid] = (_Float16)0.0f;

    // per-gate streamed row pointers: row g*128+j, K-quarter q (32 halfs=64B)
    const float4* wp0 = (const float4*)(Wh + (0 * Hn + j) * Hn + q * 32);
    const float4* wp1 = (const float4*)(Wh + (1 * Hn + j) * Hn + q * 32);
    const float4* wp2 = (const float4*)(Wh + (2 * Hn + j) * Hn + q * 32);
    const float4* wp3 = (const float4*)(Wh + (3 * Hn + j) * Hn + q * 32);

    float c_ = 0.0f;
    float hlast = 0.0f;
    float* out_base = out + b * Sn * Hn;
    __syncthreads();

    for (int s = 0; s < Sn; s++) {
        // launder: loads below stay in-loop (b128 from L1/L2), cannot be
        // hoisted into registers (would re-trigger R5/R6 AGPR parking).
        asm volatile("" : "+v"(wp0), "+v"(wp1), "+v"(wp2), "+v"(wp3));

        float gx0 = 0.f, gx1 = 0.f, gx2 = 0.f, gx3 = 0.f;
        if (tid < Hn) {
            const float* gp = Gtab + xb[s] * G4H + j;
            gx0 = gp[0]; gx1 = gp[128]; gx2 = gp[256]; gx3 = gp[384];
        }

        // weight chunks: 4 gates x 4 x b128 (8 halfs each) -- batched issue
        float4 w0[4], w1[4], w2[4], w3[4];
#pragma unroll
        for (int i = 0; i < 4; i++) { w0[i] = wp0[i]; w1[i] = wp1[i]; }
#pragma unroll
        for (int i = 0; i < 4; i++) { w2[i] = wp2[i]; w3[i] = wp3[i]; }

        // h chunk: 32 halfs = 4 x b128, wave-uniform address (broadcast)
        const float4* h4 = ((const float4*)hbuf) + q * 4;
        float4 hh[4];
#pragma unroll
        for (int i = 0; i < 4; i++) hh[i] = h4[i];

        float p0 = 0.f, p1 = 0.f, p2 = 0.f, p3 = 0.f;
#pragma unroll
        for (int i = 0; i < 4; i++) {
            p0 = dot2f(w0[i].x, hh[i].x, p0); p0 = dot2f(w0[i].y, hh[i].y, p0);
            p0 = dot2f(w0[i].z, hh[i].z, p0); p0 = dot2f(w0[i].w, hh[i].w, p0);
            p1 = dot2f(w1[i].x, hh[i].x, p1); p1 = dot2f(w1[i].y, hh[i].y, p1);
            p1 = dot2f(w1[i].z, hh[i].z, p1); p1 = dot2f(w1[i].w, hh[i].w, p1);
            p2 = dot2f(w2[i].x, hh[i].x, p2); p2 = dot2f(w2[i].y, hh[i].y, p2);
            p2 = dot2f(w2[i].z, hh[i].z, p2); p2 = dot2f(w2[i].w, hh[i].w, p2);
            p3 = dot2f(w3[i].x, hh[i].x, p3); p3 = dot2f(w3[i].y, hh[i].y, p3);
            p3 = dot2f(w3[i].z, hh[i].z, p3); p3 = dot2f(w3[i].w, hh[i].w, p3);
        }
        part[0 * 4 + q][j] = p0;
        part[1 * 4 + q][j] = p1;
        part[2 * 4 + q][j] = p2;
        part[3 * 4 + q][j] = p3;
        __syncthreads();
        if (tid < Hn) {
            float gi = gx0 + part[0][j]  + part[1][j]  + part[2][j]  + part[3][j];
            float gf = gx1 + part[4][j]  + part[5][j]  + part[6][j]  + part[7][j];
            float gg = gx2 + part[8][j]  + part[9][j]  + part[10][j] + part[11][j];
            float go = gx3 + part[12][j] + part[13][j] + part[14][j] + part[15][j];
            c_ = fsigmoid(gf) * c_ + fsigmoid(gi) * ftanh(gg);
            float h = fsigmoid(go) * ftanh(c_);
            hlast = h;
            hbuf[j] = (_Float16)h;          // fp16 mirror for next step's dot
            out_base[s * Hn + j] = h;       // full-precision h downstream
        }
        __syncthreads();
    }
    if (tid < Hn) {
        hT[b * Hn + j] = hlast;
        cT[b * Hn + j] = c_;
    }
}

// ---------------------------------------------------------------------------
// Kernel C: q = out@Wq.T + bq ; k = out@Wk.T + bk
// ---------------------------------------------------------------------------
__global__ __launch_bounds__(256) void k_qk(
        const float* __restrict__ out, const float* __restrict__ Wq,
        const float* __restrict__ bq, const float* __restrict__ Wk,
        const float* __restrict__ bk, float* __restrict__ qo, float* __restrict__ ko) {
    int bs  = blockIdx.x;
    int tid = threadIdx.x;
    __shared__ float o[Hn];
    if (tid < Hn) o[tid] = out[bs * Hn + tid];
    __syncthreads();
    int h = tid & 127;
    const float* Wm = (tid < Hn) ? Wq : Wk;
    const float* bm = (tid < Hn) ? bq : bk;
    const float4* wr = (const float4*)(Wm + h * Hn);
    float acc = bm[h];
#pragma unroll
    for (int i = 0; i < Hn / 4; i++) {
        float4 w4 = wr[i];
        acc += w4.x * o[4*i] + w4.y * o[4*i+1] + w4.z * o[4*i+2] + w4.w * o[4*i+3];
    }
    float* dst = (tid < Hn) ? qo : ko;
    dst[bs * Hn + h] = acc;
}

// ---------------------------------------------------------------------------
// Kernel D: Bahdanau scores + causal softmax + ctx. Block per (b,t).
// ---------------------------------------------------------------------------
__global__ __launch_bounds__(512) void k_attn(
        const float* __restrict__ qo, const float* __restrict__ ko,
        const float* __restrict__ vvec, const float* __restrict__ out,
        float* __restrict__ ctx) {
    int b   = blockIdx.x >> 9;
    int t   = blockIdx.x & (Sn - 1);
    int tid = threadIdx.x;
    __shared__ float qs[Hn];
    __shared__ float vs[Hn];
    __shared__ float sc[Sn];
    __shared__ float red[512];
    __shared__ float part[16][Hn];

    if (tid < Hn) {
        qs[tid] = qo[(b * Sn + t) * Hn + tid];
        vs[tid] = vvec[tid];
    }
    __syncthreads();

    float a = -1e30f;
    if (tid <= t) {
        const float4* kr = (const float4*)(ko + (b * Sn + tid) * Hn);
        float s = 0.0f;
#pragma unroll
        for (int u = 0; u < Hn / 4; u++) {
            float4 k4 = kr[u];
            s += vs[4*u]   * ftanh(qs[4*u]   + k4.x);
            s += vs[4*u+1] * ftanh(qs[4*u+1] + k4.y);
            s += vs[4*u+2] * ftanh(qs[4*u+2] + k4.z);
            s += vs[4*u+3] * ftanh(qs[4*u+3] + k4.w);
        }
        sc[tid] = s;
        a = s;
    }
    red[tid] = a;
    __syncthreads();
    for (int off = 256; off > 0; off >>= 1) {
        if (tid < off) red[tid] = fmaxf(red[tid], red[tid + off]);
        __syncthreads();
    }
    float m = red[0];
    __syncthreads();

    float ev = 0.0f;
    if (tid <= t) {
        ev = __expf(sc[tid] - m);
        sc[tid] = ev;
    }
    red[tid] = ev;
    __syncthreads();
    for (int off = 256; off > 0; off >>= 1) {
        if (tid < off) red[tid] += red[tid + off];
        __syncthreads();
    }
    float inv = 1.0f / red[0];
    __syncthreads();

    int hq = tid & 31;
    int is = tid >> 5;
    float4 acc = {0.0f, 0.0f, 0.0f, 0.0f};
    const float4* ob = (const float4*)(out + b * Sn * Hn);
    for (int i = is; i <= t; i += 16) {
        float s = sc[i];
        float4 o4 = ob[i * (Hn / 4) + hq];
        acc.x += s * o4.x; acc.y += s * o4.y;
        acc.z += s * o4.z; acc.w += s * o4.w;
    }
    ((float4*)part[is])[hq] = acc;
    __syncthreads();
    if (tid < Hn) {
        float ssum = 0.0f;
#pragma unroll
        for (int r = 0; r < 16; r++) ssum += part[r][tid];
        ctx[(b * Sn + t) * Hn + tid] = ssum * inv;
    }
}

// ---------------------------------------------------------------------------
// Kernel E: logits = [out, ctx] @ Wf.T + bf. Block per (b,s), 128 threads.
// ---------------------------------------------------------------------------
__global__ __launch_bounds__(128) void k_final(
        const float* __restrict__ out, const float* __restrict__ ctx,
        const float* __restrict__ Wf, const float* __restrict__ bf,
        float* __restrict__ logits) {
    int bs  = blockIdx.x;
    int tid = threadIdx.x;
    __shared__ float oc[2 * Hn];
    oc[tid]      = out[bs * Hn + tid];
    oc[tid + Hn] = ctx[bs * Hn + tid];
    __syncthreads();
    const float4* wr = (const float4*)(Wf + tid * 2 * Hn);
    float acc = bf[tid];
#pragma unroll
    for (int i = 0; i < (2 * Hn) / 4; i++) {
        float4 w4 = wr[i];
        acc += w4.x * oc[4*i] + w4.y * oc[4*i+1] + w4.z * oc[4*i+2] + w4.w * oc[4*i+3];
    }
    logits[bs * Vn + tid] = acc;
}

extern "C" void kernel_launch(void* const* d_in, const int* in_sizes, int n_in,
                              void* d_out, int out_size, void* d_ws, size_t ws_size,
                              hipStream_t stream) {
    const int*   x   = (const int*)d_in[0];
    const float* emb = (const float*)d_in[1];
    const float* Wih = (const float*)d_in[2];
    const float* Whh = (const float*)d_in[3];
    const float* bih = (const float*)d_in[4];
    const float* bhh = (const float*)d_in[5];
    const float* Wq  = (const float*)d_in[6];
    const float* bq  = (const float*)d_in[7];
    const float* Wk  = (const float*)d_in[8];
    const float* bk  = (const float*)d_in[9];
    const float* v   = (const float*)d_in[10];
    const float* Wf  = (const float*)d_in[11];
    const float* bf  = (const float*)d_in[12];

    float* logits = (float*)d_out;                 // (B,S,V) = 262144
    float* hT     = logits + Bn * Sn * Vn;         // (B,H)   = 512
    float* cT     = hT + Bn * Hn;                  // (B,H)   = 512

    float* ws   = (float*)d_ws;
    float* Gtab = ws;                               // V*4H   = 65536 floats
    float* outb = ws + 65536;                       // B*S*H  = 262144
    float* qo   = ws + 65536 + 262144;
    float* ko   = ws + 65536 + 2 * 262144;
    float* ctx  = ws + 65536 + 3 * 262144;

    // fp16 W_hh (128 KB) aliases the ctx buffer: written by k_wcvt, consumed
    // by k_lstm, dead before k_attn overwrites ctx. Zero extra workspace.
    _Float16* Wh = (_Float16*)ctx;

    k_wcvt<<<64, 256, 0, stream>>>(Whh, Wh);
    k_gtab<<<Vn, 512, 0, stream>>>(emb, Wih, bih, bhh, Gtab);
    k_lstm<<<Bn, 512, 0, stream>>>(Wh, Gtab, x, outb, hT, cT);
    k_qk<<<Bn * Sn, 256, 0, stream>>>(outb, Wq, bq, Wk, bk, qo, ko);
    k_attn<<<Bn * Sn, 512, 0, stream>>>(qo, ko, v, outb, ctx);
    k_final<<<Bn * Sn, 128, 0, stream>>>(outb, ctx, Wf, bf, logits);
}

// Round 6
// 652.413 us; speedup vs baseline: 3.5183x; 3.5183x over previous
//
#include <hip/hip_runtime.h>

#define Vn 128
#define En 32
#define Hn 128
#define Bn 4
#define Sn 512
#define G4H 512   // 4*Hn

typedef _Float16 half8 __attribute__((ext_vector_type(8)));
typedef float    floatx4 __attribute__((ext_vector_type(4)));

__device__ __forceinline__ float fsigmoid(float x) {
    return 1.0f / (1.0f + __expf(-x));
}

__device__ __forceinline__ float ftanh(float x) {
    float ax = fabsf(x);
    float e  = __expf(2.0f * ax);
    float t  = 1.0f - 2.0f / (e + 1.0f);
    return copysignf(t, x);
}

// ---------------------------------------------------------------------------
// Kernel A': Gtab[v][g] = (b_ih+b_hh)[g] + sum_e emb[v][e] * W_ih[g][e]
// ---------------------------------------------------------------------------
__global__ __launch_bounds__(512) void k_gtab(
        const float* __restrict__ emb, const float* __restrict__ Wih,
        const float* __restrict__ bih, const float* __restrict__ bhh,
        float* __restrict__ Gtab) {
    int v = blockIdx.x;
    int g = threadIdx.x;
    __shared__ float e[En];
    if (g < En) e[g] = emb[v * En + g];
    __syncthreads();
    const float4* wr = (const float4*)(Wih + g * En);
    float acc = bih[g] + bhh[g];
#pragma unroll
    for (int i = 0; i < En / 4; i++) {
        float4 w4 = wr[i];
        acc += w4.x * e[4*i] + w4.y * e[4*i+1] + w4.z * e[4*i+2] + w4.w * e[4*i+3];
    }
    Gtab[v * G4H + g] = acc;
}

// ---------------------------------------------------------------------------
// Kernel B (R10): MFMA LSTM. ONE block, 512 threads, all 4 batches.
// Per step: G(512x4) = W_hh(512x128) @ H(128x4) via mfma_f32_16x16x32_f16
// (N padded to 16, cols 0..3 = batches). Wave w owns row-tiles 4w..4w+3;
// 16 A-fragments (fp16, cvt'd once in prologue) stay register-resident as
// MFMA operands -- the ONLY unit that reads AGPRs natively, ending the
// R4/R5/R6 shuttle tax and the R8/R9 per-step stream latency.
//
// Fragment maps (m89-verified D; lab-notes A/B):
//   A[row][k]: row = lane&15, k = (lane>>4)*8 + i   (i=0..7 in half8)
//   B[k][col]: col = lane&15, k = (lane>>4)*8 + i
//   D[row][col]: col = lane&15, row = (lane>>4)*4 + reg
// LDS: hbuf[4][136] fp16 (pad->16B-aligned frag reads, <=2-way banks = free);
//      gbuf[4][520] fp32 (b128 D-writes 2-way; activation reads stride-1).
// ---------------------------------------------------------------------------
__global__ __attribute__((amdgpu_flat_work_group_size(512, 512),
                          amdgpu_waves_per_eu(2, 2)))
void k_lstm(
        const float* __restrict__ Whh, const float* __restrict__ Gtab,
        const int* __restrict__ x,
        float* __restrict__ out, float* __restrict__ hT, float* __restrict__ cT) {
    int tid = threadIdx.x;
    int wv  = tid >> 6;    // wave 0..7: owns gate rows 64*wv .. 64*wv+63
    int l   = tid & 63;
    int cn  = l & 15;      // MFMA col = batch (valid if < 4)
    int kg  = l >> 4;      // k-group 0..3
    int an  = tid >> 7;    // activation: batch
    int aj  = tid & 127;   // activation: row j

    __shared__ float gbuf[4][520];                 // gate preacts (h-path)
    __shared__ alignas(16) _Float16 hbuf[4][136];  // h, fp16
    __shared__ int xb[4][512];

    for (int i = tid; i < Bn * Sn; i += 512) xb[i >> 9][i & 511] = x[i];
    for (int i = tid; i < 4 * 136; i += 512) ((_Float16*)hbuf)[i] = (_Float16)0.0f;

    // ---- prologue: A-fragments, loaded+converted ONCE (128 floats/lane) ----
    half8 af[4][4];   // [row-tile tt][k-chunk kc]
#pragma unroll
    for (int tt = 0; tt < 4; tt++) {
#pragma unroll
        for (int kc = 0; kc < 4; kc++) {
            int row = wv * 64 + tt * 16 + cn;
            int kb  = kc * 32 + kg * 8;
            const float4* p = (const float4*)(Whh + row * Hn + kb);
            float4 lo = p[0], hi = p[1];
            half8 a = { (_Float16)lo.x, (_Float16)lo.y, (_Float16)lo.z, (_Float16)lo.w,
                        (_Float16)hi.x, (_Float16)hi.y, (_Float16)hi.z, (_Float16)hi.w };
            af[tt][kc] = a;
        }
    }

    float c_ = 0.0f;
    float hlast = 0.0f;
    __syncthreads();

    for (int s = 0; s < Sn; s++) {
        // prefetch x-path preacts (independent of h -> overlaps MFMA phase)
        int xs = xb[an][s];
        const float* gp = Gtab + xs * G4H + aj;
        float gx0 = gp[0], gx1 = gp[128], gx2 = gp[256], gx3 = gp[384];

        // B-fragments from hbuf (16 active lanes/wave; <=2-way banks)
        half8 bf[4];
#pragma unroll
        for (int kc = 0; kc < 4; kc++) {
            half8 bz = { (_Float16)0, (_Float16)0, (_Float16)0, (_Float16)0,
                         (_Float16)0, (_Float16)0, (_Float16)0, (_Float16)0 };
            if (cn < 4) bz = *(const half8*)&hbuf[cn][kc * 32 + kg * 8];
            bf[kc] = bz;
        }

        // 16 MFMAs: 4 row-tiles x 4 K-chunks, fp32 accumulate
#pragma unroll
        for (int tt = 0; tt < 4; tt++) {
            floatx4 d = { 0.f, 0.f, 0.f, 0.f };
#pragma unroll
            for (int kc = 0; kc < 4; kc++)
                d = __builtin_amdgcn_mfma_f32_16x16x32_f16(af[tt][kc], bf[kc], d, 0, 0, 0);
            if (cn < 4) {
                int rb = wv * 64 + tt * 16 + kg * 4;   // 16B-aligned
                *(floatx4*)&gbuf[cn][rb] = d;
            }
        }
        __syncthreads();

        // activation: thread (an, aj); gbuf reads stride-1/lane (no conflict)
        float gi = gx0 + gbuf[an][aj];
        float gf = gx1 + gbuf[an][aj + 128];
        float gg = gx2 + gbuf[an][aj + 256];
        float go = gx3 + gbuf[an][aj + 384];
        c_ = fsigmoid(gf) * c_ + fsigmoid(gi) * ftanh(gg);
        float h = fsigmoid(go) * ftanh(c_);
        hlast = h;
        hbuf[an][aj] = (_Float16)h;
        out[an * Sn * Hn + s * Hn + aj] = h;
        __syncthreads();
    }
    hT[an * Hn + aj] = hlast;
    cT[an * Hn + aj] = c_;
}

// ---------------------------------------------------------------------------
// Kernel C: q = out@Wq.T + bq ; k = out@Wk.T + bk
// ---------------------------------------------------------------------------
__global__ __launch_bounds__(256) void k_qk(
        const float* __restrict__ out, const float* __restrict__ Wq,
        const float* __restrict__ bq, const float* __restrict__ Wk,
        const float* __restrict__ bk, float* __restrict__ qo, float* __restrict__ ko) {
    int bs  = blockIdx.x;
    int tid = threadIdx.x;
    __shared__ float o[Hn];
    if (tid < Hn) o[tid] = out[bs * Hn + tid];
    __syncthreads();
    int h = tid & 127;
    const float* Wm = (tid < Hn) ? Wq : Wk;
    const float* bm = (tid < Hn) ? bq : bk;
    const float4* wr = (const float4*)(Wm + h * Hn);
    float acc = bm[h];
#pragma unroll
    for (int i = 0; i < Hn / 4; i++) {
        float4 w4 = wr[i];
        acc += w4.x * o[4*i] + w4.y * o[4*i+1] + w4.z * o[4*i+2] + w4.w * o[4*i+3];
    }
    float* dst = (tid < Hn) ? qo : ko;
    dst[bs * Hn + h] = acc;
}

// ---------------------------------------------------------------------------
// Kernel D: Bahdanau scores + causal softmax + ctx. Block per (b,t).
// ---------------------------------------------------------------------------
__global__ __launch_bounds__(512) void k_attn(
        const float* __restrict__ qo, const float* __restrict__ ko,
        const float* __restrict__ vvec, const float* __restrict__ out,
        float* __restrict__ ctx) {
    int b   = blockIdx.x >> 9;
    int t   = blockIdx.x & (Sn - 1);
    int tid = threadIdx.x;
    __shared__ float qs[Hn];
    __shared__ float vs[Hn];
    __shared__ float sc[Sn];
    __shared__ float red[512];
    __shared__ float part[16][Hn];

    if (tid < Hn) {
        qs[tid] = qo[(b * Sn + t) * Hn + tid];
        vs[tid] = vvec[tid];
    }
    __syncthreads();

    float a = -1e30f;
    if (tid <= t) {
        const float4* kr = (const float4*)(ko + (b * Sn + tid) * Hn);
        float s = 0.0f;
#pragma unroll
        for (int u = 0; u < Hn / 4; u++) {
            float4 k4 = kr[u];
            s += vs[4*u]   * ftanh(qs[4*u]   + k4.x);
            s += vs[4*u+1] * ftanh(qs[4*u+1] + k4.y);
            s += vs[4*u+2] * ftanh(qs[4*u+2] + k4.z);
            s += vs[4*u+3] * ftanh(qs[4*u+3] + k4.w);
        }
        sc[tid] = s;
        a = s;
    }
    red[tid] = a;
    __syncthreads();
    for (int off = 256; off > 0; off >>= 1) {
        if (tid < off) red[tid] = fmaxf(red[tid], red[tid + off]);
        __syncthreads();
    }
    float m = red[0];
    __syncthreads();

    float ev = 0.0f;
    if (tid <= t) {
        ev = __expf(sc[tid] - m);
        sc[tid] = ev;
    }
    red[tid] = ev;
    __syncthreads();
    for (int off = 256; off > 0; off >>= 1) {
        if (tid < off) red[tid] += red[tid + off];
        __syncthreads();
    }
    float inv = 1.0f / red[0];
    __syncthreads();

    int hq = tid & 31;
    int is = tid >> 5;
    float4 acc = {0.0f, 0.0f, 0.0f, 0.0f};
    const float4* ob = (const float4*)(out + b * Sn * Hn);
    for (int i = is; i <= t; i += 16) {
        float s = sc[i];
        float4 o4 = ob[i * (Hn / 4) + hq];
        acc.x += s * o4.x; acc.y += s * o4.y;
        acc.z += s * o4.z; acc.w += s * o4.w;
    }
    ((float4*)part[is])[hq] = acc;
    __syncthreads();
    if (tid < Hn) {
        float ssum = 0.0f;
#pragma unroll
        for (int r = 0; r < 16; r++) ssum += part[r][tid];
        ctx[(b * Sn + t) * Hn + tid] = ssum * inv;
    }
}

// ---------------------------------------------------------------------------
// Kernel E: logits = [out, ctx] @ Wf.T + bf. Block per (b,s), 128 threads.
// ---------------------------------------------------------------------------
__global__ __launch_bounds__(128) void k_final(
        const float* __restrict__ out, const float* __restrict__ ctx,
        const float* __restrict__ Wf, const float* __restrict__ bf,
        float* __restrict__ logits) {
    int bs  = blockIdx.x;
    int tid = threadIdx.x;
    __shared__ float oc[2 * Hn];
    oc[tid]      = out[bs * Hn + tid];
    oc[tid + Hn] = ctx[bs * Hn + tid];
    __syncthreads();
    const float4* wr = (const float4*)(Wf + tid * 2 * Hn);
    float acc = bf[tid];
#pragma unroll
    for (int i = 0; i < (2 * Hn) / 4; i++) {
        float4 w4 = wr[i];
        acc += w4.x * oc[4*i] + w4.y * oc[4*i+1] + w4.z * oc[4*i+2] + w4.w * oc[4*i+3];
    }
    logits[bs * Vn + tid] = acc;
}

extern "C" void kernel_launch(void* const* d_in, const int* in_sizes, int n_in,
                              void* d_out, int out_size, void* d_ws, size_t ws_size,
                              hipStream_t stream) {
    const int*   x   = (const int*)d_in[0];
    const float* emb = (const float*)d_in[1];
    const float* Wih = (const float*)d_in[2];
    const float* Whh = (const float*)d_in[3];
    const float* bih = (const float*)d_in[4];
    const float* bhh = (const float*)d_in[5];
    const float* Wq  = (const float*)d_in[6];
    const float* bq  = (const float*)d_in[7];
    const float* Wk  = (const float*)d_in[8];
    const float* bk  = (const float*)d_in[9];
    const float* v   = (const float*)d_in[10];
    const float* Wf  = (const float*)d_in[11];
    const float* bf  = (const float*)d_in[12];

    float* logits = (float*)d_out;                 // (B,S,V) = 262144
    float* hT     = logits + Bn * Sn * Vn;         // (B,H)   = 512
    float* cT     = hT + Bn * Hn;                  // (B,H)   = 512

    float* ws   = (float*)d_ws;
    float* Gtab = ws;                               // V*4H   = 65536 floats
    float* outb = ws + 65536;                       // B*S*H  = 262144
    float* qo   = ws + 65536 + 262144;
    float* ko   = ws + 65536 + 2 * 262144;
    float* ctx  = ws + 65536 + 3 * 262144;

    k_gtab<<<Vn, 512, 0, stream>>>(emb, Wih, bih, bhh, Gtab);
    k_lstm<<<1, 512, 0, stream>>>(Whh, Gtab, x, outb, hT, cT);
    k_qk<<<Bn * Sn, 256, 0, stream>>>(outb, Wq, bq, Wk, bk, qo, ko);
    k_attn<<<Bn * Sn, 512, 0, stream>>>(qo, ko, v, outb, ctx);
    k_final<<<Bn * Sn, 128, 0, stream>>>(outb, ctx, Wf, bf, logits);
}